// Round 9
// baseline (297.005 us; speedup 1.0000x reference)
//
#include <hip/hip_runtime.h>
#include <hip/hip_bf16.h>
#include <stdint.h>

// MultiHeadAttention: B=32, NQ=T=1024, E=128, H=8, dk=dv=16
// Inputs FLOAT32, output FLOAT32. Internal bf16 MFMA.
// S^T via mfma_f32_32x32x16_bf16 (K=16 == dk); PV + denom via 16x16x32.
// Softmax exp2-domain, NO max-bias (self-normalizing; denominator division
// restores scale). LUT AND-masking.
// v9: SPLIT maskpack out of the proj grid. R8 counters showed the fused
// kernel's 53 KB LDS (proj's WtLds+Cxf) throttled the 2048 streaming
// mask-pack blocks to 3 blocks/CU (79 us total). Separate maskpack_k has
// ZERO LDS, ~16 VGPR -> 8 blocks/CU x 4 waves = 32 waves/CU, one full
// residency round, streams 33.5 MB at full BW.
// attn v8 (unchanged, first confirmed attn win): 64 q/wave, 1 wave/block,
// 4096 blocks, XCD swizzle, s_setprio, single-buffered K/V/mask with
// placed prefetch, no cb16 bank, __launch_bounds__(64,4).
// R2 lesson: VGPR floor below natural live set spills catastrophically.
// R4 lesson: 4-wave LDS-staged K/V regressed; 1-wave reg-resident is right.
// 4 launches: maskpack -> projqkv -> flash-attn -> out-proj.

typedef __attribute__((ext_vector_type(8))) short bf16x8;    // MFMA A/B frag
typedef __attribute__((ext_vector_type(4))) float f32x4;     // 16x16 C/D frag
typedef __attribute__((ext_vector_type(16))) float f32x16;   // 32x32 C/D frag

#define QSCALE 0.36067376022224085f   // (1/sqrt(16)) * log2(e)
#define EXP2(x) __builtin_amdgcn_exp2f(x)   // raw v_exp_f32 (2^x)
#define PSTRIDE 68                     // ushorts; 34 dwords = 2 mod 32 banks

__device__ __forceinline__ unsigned short f2bf(float x) {
  union { __hip_bfloat16 h; unsigned short u; } cv;
  cv.h = __float2bfloat16(x);
  return cv.u;
}
// pack two f32 -> two bf16 (round-half-up): low=a, high=b
__device__ __forceinline__ unsigned int pk2bf(float a, float b) {
  unsigned int ua = __float_as_uint(a) + 0x8000u;
  unsigned int ub = __float_as_uint(b) + 0x8000u;
  return __builtin_amdgcn_perm(ub, ua, 0x07060302u);
}
// pack two f32 -> two bf16 (truncate; 1 instr): low=a, high=b
__device__ __forceinline__ unsigned int pk2bf_t(float a, float b) {
  return __builtin_amdgcn_perm(__float_as_uint(b), __float_as_uint(a), 0x07060302u);
}

// ---------------- mask packing (own kernel: ZERO LDS, full occupancy) ----------------
// 2048 blocks x 256 threads; 64 elems/thread -> one u64 per thread, coalesced.
__global__ __launch_bounds__(256) void maskpack_k(const void* __restrict__ mask,
                                                  unsigned long long* __restrict__ mp64) {
  const int tid = threadIdx.x;
  const int bx = blockIdx.x;
  const unsigned int* mi = (const unsigned int*)mask;
  unsigned int accv = 0;
  #pragma unroll
  for (int k = 0; k < 16; ++k) accv |= mi[k * 251];
  const bool bytemode = accv > 1u;

  const long long i0 = ((long long)bx * 256 + tid) * 64;  // elem index base
  unsigned long long out = 0;
  if (bytemode) {
    const int4* mp4 = (const int4*)((const unsigned char*)mask + i0);
    #pragma unroll
    for (int j = 0; j < 4; ++j) {
      int4 w = mp4[j];
      unsigned int ws[4] = {(unsigned)w.x, (unsigned)w.y, (unsigned)w.z, (unsigned)w.w};
      unsigned long long v = 0;
      // bytes are exactly 0x00/0x01: pack 4 byte-bools -> nibble in 3 ops
      #pragma unroll
      for (int d = 0; d < 4; ++d) {
        unsigned int t = ws[d] & 0x01010101u;
        v |= (unsigned long long)((t * 0x01020408u) >> 24) << (d*4);
      }
      out |= v << (j*16);
    }
  } else {
    const int4* mp4 = (const int4*)((const int*)mask + i0);
    #pragma unroll
    for (int j = 0; j < 4; ++j) {
      unsigned long long v = 0;
      // int32 values are exactly 0/1: direct shift-or, no compares
      #pragma unroll
      for (int d = 0; d < 4; ++d) {
        int4 w = mp4[j*4 + d];
        v |= ((unsigned long long)(unsigned)w.x) << (d*4 + 0);
        v |= ((unsigned long long)(unsigned)w.y) << (d*4 + 1);
        v |= ((unsigned long long)(unsigned)w.z) << (d*4 + 2);
        v |= ((unsigned long long)(unsigned)w.w) << (d*4 + 3);
      }
      out |= v << (j*16);
    }
  }
  // thread's 64 bits are exactly u64 word (bx*256 + tid) of mp64
  mp64[(long long)bx * 256 + tid] = out;
}

// ---------------- Q/K/V projection (1536 blocks: sel = x>>9) ----------------
__global__ __launch_bounds__(256) void proj_k(const float* __restrict__ qp,
                                              const float* __restrict__ hp,
                                              const float* __restrict__ wqp,
                                              const float* __restrict__ wkp,
                                              const float* __restrict__ wvp,
                                              unsigned short* __restrict__ Qb,
                                              unsigned short* __restrict__ Kb,
                                              unsigned short* __restrict__ Vt) {
  __shared__ unsigned short WtLds[128 * 136];
  __shared__ __align__(16) unsigned short Cxf[9216];
  const int tid = threadIdx.x;
  const int wave = tid >> 6, lane = tid & 63;
  const int llo4 = lane & 15, lhi4 = lane >> 4;
  const int xb = blockIdx.x & 511;
  const int sel = blockIdx.x >> 9;
  const int m0 = xb * 64;
  const int b = m0 >> 10, row0 = m0 & 1023;
  const float* A = (sel == 0) ? qp : hp;
  const float* W = (sel == 0) ? wqp : (sel == 1) ? wkp : wvp;
  const float wscale = (sel == 0) ? QSCALE : 1.0f;

  #pragma unroll
  for (int i = 0; i < 8; ++i) {
    int base = (tid + i * 256) * 8;
    float4 w0 = *(const float4*)&W[base];
    float4 w1 = *(const float4*)&W[base + 4];
    float wv8[8] = {w0.x, w0.y, w0.z, w0.w, w1.x, w1.y, w1.z, w1.w};
    // paired half-up pack: consecutive j -> consecutive kk rows, same e col
    #pragma unroll
    for (int j = 0; j < 8; j += 2) {
      unsigned int pk = pk2bf(wv8[j] * wscale, wv8[j+1] * wscale);
      int idx = base + j;
      int h = idx >> 11, e = (idx >> 4) & 127, kk = idx & 15;
      WtLds[(h*16 + kk    ) * 136 + e] = (unsigned short)pk;
      WtLds[(h*16 + kk + 1) * 136 + e] = (unsigned short)(pk >> 16);
    }
  }
  #pragma unroll
  for (int i = 0; i < 4; ++i) {
    int r = (tid >> 4) + i * 16;
    int c = (tid & 15) * 8;
    float4 a0 = *(const float4*)&A[(m0 + r) * 128 + c];
    float4 a1 = *(const float4*)&A[(m0 + r) * 128 + c + 4];
    union { unsigned int u[4]; bf16x8 v; } cvt;
    cvt.u[0] = pk2bf(a0.x, a0.y);
    cvt.u[1] = pk2bf(a0.z, a0.w);
    cvt.u[2] = pk2bf(a1.x, a1.y);
    cvt.u[3] = pk2bf(a1.z, a1.w);
    *(bf16x8*)&Cxf[r * 136 + c] = cvt.v;
  }
  __syncthreads();

  const int n0 = wave * 32;
  f32x4 acc[4][2] = {};
  #pragma unroll
  for (int kk = 0; kk < 128; kk += 32) {
    bf16x8 af[4], bfr[2];
    #pragma unroll
    for (int mi2 = 0; mi2 < 4; ++mi2)
      af[mi2] = *(const bf16x8*)&Cxf[(mi2*16 + llo4)*136 + kk + lhi4*8];
    #pragma unroll
    for (int ni = 0; ni < 2; ++ni)
      bfr[ni] = *(const bf16x8*)&WtLds[(n0 + ni*16 + llo4)*136 + kk + lhi4*8];
    #pragma unroll
    for (int mi2 = 0; mi2 < 4; ++mi2)
      #pragma unroll
      for (int ni = 0; ni < 2; ++ni)
        acc[mi2][ni] = __builtin_amdgcn_mfma_f32_16x16x32_bf16(af[mi2], bfr[ni], acc[mi2][ni], 0, 0, 0);
  }

  __syncthreads();
  if (sel < 2) {
    unsigned short* Cb = sel ? Kb : Qb;
    #pragma unroll
    for (int mi2 = 0; mi2 < 4; ++mi2)
      #pragma unroll
      for (int ni = 0; ni < 2; ++ni) {
        int n = n0 + ni*16 + llo4;
        int rb = (mi2*16 + lhi4*4);
        unsigned int p01 = pk2bf(acc[mi2][ni][0], acc[mi2][ni][1]);
        unsigned int p23 = pk2bf(acc[mi2][ni][2], acc[mi2][ni][3]);
        Cxf[(rb + 0)*136 + n] = (unsigned short)p01;
        Cxf[(rb + 1)*136 + n] = (unsigned short)(p01 >> 16);
        Cxf[(rb + 2)*136 + n] = (unsigned short)p23;
        Cxf[(rb + 3)*136 + n] = (unsigned short)(p23 >> 16);
      }
    __syncthreads();
    #pragma unroll
    for (int it = 0; it < 4; ++it) {
      int u = tid + it*256;
      int h = u >> 7, rk = u & 127, row = rk >> 1, kh = rk & 1;
      bf16x8 vv = *(const bf16x8*)&Cxf[row*136 + h*16 + kh*8];
      *(bf16x8*)&Cb[((b*8 + h)*1024 + row0 + row)*16 + kh*8] = vv;
    }
  } else {
    #pragma unroll
    for (int mi2 = 0; mi2 < 4; ++mi2)
      #pragma unroll
      for (int ni = 0; ni < 2; ++ni) {
        int n = n0 + ni*16 + llo4;
        uint2 pk;
        pk.x = pk2bf(acc[mi2][ni][0], acc[mi2][ni][1]);
        pk.y = pk2bf(acc[mi2][ni][2], acc[mi2][ni][3]);
        *(uint2*)&Cxf[n*72 + mi2*16 + lhi4*4] = pk;
      }
    __syncthreads();
    #pragma unroll
    for (int it = 0; it < 4; ++it) {
      int u = tid + it*256;
      int n = u >> 3, tc = u & 7;
      int h = n >> 4, k = n & 15;
      bf16x8 vv = *(const bf16x8*)&Cxf[n*72 + tc*8];
      *(bf16x8*)&Vt[((b*8 + h)*16 + k)*1024 + row0 + tc*8] = vv;
    }
  }
}

// ---------------- flash attention (1 wave/block, 64 q/wave, LUT mask) ----------------
// 4096 blocks (1-D). XCD-swizzled so each XCD owns whole (b,h) K/V panels.
// Single-buffered K/V/mask with placed prefetch. No softmax bias (see header).
__global__ __launch_bounds__(64, 4) void attn_k(const unsigned short* __restrict__ Qb,
                                                const unsigned short* __restrict__ Kb,
                                                const unsigned short* __restrict__ Vtb,
                                                const unsigned long long* __restrict__ mp64,
                                                unsigned short* __restrict__ heads) {
  __shared__ __align__(16) unsigned short Pw[32 * PSTRIDE]; // [q32][t64]
  __shared__ __align__(8) uint2 mlut[16];  // nibble -> 4 halfword AND-masks
  const int lane = threadIdx.x;
  const int llo4 = lane & 15, lhi4 = lane >> 4;
  const int llo5 = lane & 31, lhi5 = lane >> 5;
  // bijective XCD swizzle: 4096 blocks, 8 XCDs -> 512 contiguous per XCD
  const int bid = blockIdx.x;
  const int nid = (bid & 7) * 512 + (bid >> 3);
  const int q0 = (nid & 15) * 64;       // q-tile fastest: 16 tiles share (b,h)
  const int b  = (nid >> 4) & 31;
  const int h  = nid >> 9;
  const int bh = b * 8 + h;
  const unsigned long long* mp_base = &mp64[((b << 10) + q0 + llo5) * 16];
  const unsigned short* Kbase = &Kb[(bh * 1024 + llo5) * 16 + lhi5 * 8];
  const unsigned short* Vbase = &Vtb[(bh * 16 + llo4) * 1024 + lhi4 * 8];

  if (lane < 16) {
    unsigned int n = lane;
    unsigned int h0 = (n & 1u) ? 0u : 0xFFFFu;
    unsigned int h1 = (n & 2u) ? 0u : 0xFFFFu;
    unsigned int h2 = (n & 4u) ? 0u : 0xFFFFu;
    unsigned int h3 = (n & 8u) ? 0u : 0xFFFFu;
    mlut[lane] = make_uint2(h0 | (h1 << 16), h2 | (h3 << 16));
  }
  // single wave: LDS write->read ordering handled by in-order DS, no barrier

  // Q^T B-frags for the two q-halves (32 q wide each, k = lhi5*8+j covers dk=16)
  bf16x8 qf[2];
  #pragma unroll
  for (int qh = 0; qh < 2; ++qh)
    qf[qh] = *(const bf16x8*)&Qb[(bh * 1024 + q0 + qh*32 + llo5) * 16 + lhi5 * 8];

  bf16x8 ones;
  #pragma unroll
  for (int j = 0; j < 8; ++j) ones[j] = (short)0x3F80;  // bf16 1.0

  f32x4 ot[2][2] = {};    // O^T per [q-half][16-q frag]
  f32x4 lacc[2][2] = {};  // denominators

  // S-MFMA (zero C aliasing D; no bias) + exp2 + LUT-mask + pack to Pw
  auto spack = [&](const bf16x8& kfr, const bf16x8& q8, unsigned int mhalf, int ttp) {
    f32x16 st = {};   // C=0 aliased with D: no constant register bank
    __builtin_amdgcn_s_setprio(1);
    st = __builtin_amdgcn_mfma_f32_32x32x16_bf16(kfr, q8, st, 0, 0, 0);
    __builtin_amdgcn_s_setprio(0);
    const unsigned int m32 = mhalf >> (lhi5 * 4);
    #pragma unroll
    for (int g = 0; g < 4; ++g) {
      unsigned int nib = (m32 >> (g*8)) & 0xFu;
      uint2 am = mlut[nib];
      uint2 d;
      d.x = pk2bf_t(EXP2(st[g*4 + 0]), EXP2(st[g*4 + 1])) & am.x;
      d.y = pk2bf_t(EXP2(st[g*4 + 2]), EXP2(st[g*4 + 3])) & am.y;
      *(uint2*)&Pw[llo5 * PSTRIDE + ttp*32 + lhi5*4 + g*8] = d;
    }
  };
  // O^T += V^T * P^T ; l += ones * P^T
  auto pv = [&](f32x4 (&otq)[2], f32x4 (&laq)[2], const bf16x8& v0, const bf16x8& v1) {
    __builtin_amdgcn_s_setprio(1);
    #pragma unroll
    for (int kt = 0; kt < 2; ++kt) {
      const bf16x8& vv = kt ? v1 : v0;
      #pragma unroll
      for (int qn = 0; qn < 2; ++qn) {
        const unsigned short* pp = &Pw[(qn*16 + llo4) * PSTRIDE + kt*32 + lhi4*8];
        uint2 p0 = *(const uint2*)pp;
        uint2 p1 = *(const uint2*)(pp + 4);
        union { uint2 u[2]; bf16x8 v; } pf;
        pf.u[0] = p0; pf.u[1] = p1;
        otq[qn] = __builtin_amdgcn_mfma_f32_16x16x32_bf16(vv,   pf.v, otq[qn], 0, 0, 0);
        laq[qn] = __builtin_amdgcn_mfma_f32_16x16x32_bf16(ones, pf.v, laq[qn], 0, 0, 0);
      }
    }
    __builtin_amdgcn_s_setprio(0);
  };

  // prologue: tile-0 K/V/mask (single buffers)
  bf16x8 kf0 = *(const bf16x8*)&Kbase[0];
  bf16x8 kf1 = *(const bf16x8*)&Kbase[32 * 16];
  bf16x8 vf0 = *(const bf16x8*)&Vbase[0];
  bf16x8 vf1 = *(const bf16x8*)&Vbase[32];
  unsigned long long mw0 = mp_base[0];
  unsigned long long mw1 = mp_base[512];

  #pragma unroll 1
  for (int tw = 0; tw < 16; ++tw) {
    const int tn = (tw + 1) & 15;   // wrap keeps last prefetch in-bounds

    // qh0: S + pack + PV
    spack(kf0, qf[0], (unsigned int)mw0, 0);
    spack(kf1, qf[0], (unsigned int)(mw0 >> 32), 1);
    pv(ot[0], lacc[0], vf0, vf1);
    // qh1: S + pack
    spack(kf0, qf[1], (unsigned int)mw1, 0);
    spack(kf1, qf[1], (unsigned int)(mw1 >> 32), 1);
    // kf/mw dead here -> prefetch next tile into the SAME registers
    // (latency covered by qh1's PV below)
    kf0 = *(const bf16x8*)&Kbase[(tn * 64) * 16];
    kf1 = *(const bf16x8*)&Kbase[(tn * 64 + 32) * 16];
    mw0 = mp_base[tn];
    mw1 = mp_base[512 + tn];
    // qh1: PV
    pv(ot[1], lacc[1], vf0, vf1);
    // vf dead here -> prefetch next V (covered by next tile's qh0 S+pack)
    vf0 = *(const bf16x8*)&Vbase[tn * 64];
    vf1 = *(const bf16x8*)&Vbase[tn * 64 + 32];
  }

  #pragma unroll
  for (int qh = 0; qh < 2; ++qh)
    #pragma unroll
    for (int qn = 0; qn < 2; ++qn) {
      float l = lacc[qh][qn][0];
      float inv = l > 0.f ? 1.f / l : 0.f;
      f32x4 o = ot[qh][qn] * inv;
      uint2 d;
      d.x = pk2bf(o[0], o[1]);
      d.y = pk2bf(o[2], o[3]);
      *(uint2*)&heads[((b << 10) + q0 + qh*32 + qn*16 + llo4) * 128 + h*16 + lhi4*4] = d;
    }
}

// ---------------- output projection ----------------
__global__ __launch_bounds__(256) void outproj_k(const unsigned short* __restrict__ Av,
                                                 const float* __restrict__ W,
                                                 float* __restrict__ Co) {
  __shared__ unsigned short WtLds[128 * 136];
  __shared__ __align__(16) unsigned short Cxf[9216];
  const int tid = threadIdx.x;
  const int wave = tid >> 6, lane = tid & 63;
  const int llo4 = lane & 15, lhi4 = lane >> 4;
  const int m0 = blockIdx.x * 64;

  #pragma unroll
  for (int i = 0; i < 8; ++i) {
    int base = (tid + i * 256) * 8;
    float4 w0 = *(const float4*)&W[base];
    float4 w1 = *(const float4*)&W[base + 4];
    float wv8[8] = {w0.x, w0.y, w0.z, w0.w, w1.x, w1.y, w1.z, w1.w};
    // paired pack: consecutive idx -> consecutive rows, same col
    #pragma unroll
    for (int j = 0; j < 8; j += 2) {
      unsigned int pk = pk2bf(wv8[j], wv8[j+1]);
      int idx = base + j;
      WtLds[((idx & 127)    ) * 136 + (idx >> 7)] = (unsigned short)pk;
      WtLds[((idx & 127) + 1) * 136 + (idx >> 7)] = (unsigned short)(pk >> 16);
    }
  }
  #pragma unroll
  for (int i = 0; i < 4; ++i) {
    int r = (tid >> 4) + i * 16;
    int c = (tid & 15) * 8;
    *(bf16x8*)&Cxf[r * 136 + c] = *(const bf16x8*)&Av[(m0 + r) * 128 + c];
  }
  __syncthreads();

  const int n0 = wave * 32;
  f32x4 acc[4][2] = {};
  #pragma unroll
  for (int kk = 0; kk < 128; kk += 32) {
    bf16x8 af[4], bfr[2];
    #pragma unroll
    for (int mi2 = 0; mi2 < 4; ++mi2)
      af[mi2] = *(const bf16x8*)&Cxf[(mi2*16 + llo4)*136 + kk + lhi4*8];
    #pragma unroll
    for (int ni = 0; ni < 2; ++ni)
      bfr[ni] = *(const bf16x8*)&WtLds[(n0 + ni*16 + llo4)*136 + kk + lhi4*8];
    #pragma unroll
    for (int mi2 = 0; mi2 < 4; ++mi2)
      #pragma unroll
      for (int ni = 0; ni < 2; ++ni)
        acc[mi2][ni] = __builtin_amdgcn_mfma_f32_16x16x32_bf16(af[mi2], bfr[ni], acc[mi2][ni], 0, 0, 0);
  }
  #pragma unroll
  for (int mi2 = 0; mi2 < 4; ++mi2)
    #pragma unroll
    for (int ni = 0; ni < 2; ++ni) {
      int n = n0 + ni*16 + llo4;
      int mbase = m0 + mi2*16 + lhi4*4;
      #pragma unroll
      for (int r = 0; r < 4; ++r)
        Co[(mbase + r) * 128 + n] = acc[mi2][ni][r];
    }
}

extern "C" void kernel_launch(void* const* d_in, const int* in_sizes, int n_in,
                              void* d_out, int out_size, void* d_ws, size_t ws_size,
                              hipStream_t stream) {
  const float* q  = (const float*)d_in[0];
  const float* hh = (const float*)d_in[1];
  const void*  mk = d_in[2];
  const float* wq = (const float*)d_in[3];
  const float* wk = (const float*)d_in[4];
  const float* wv = (const float*)d_in[5];
  const float* wo = (const float*)d_in[6];
  float* out = (float*)d_out;

  unsigned short* Qb = (unsigned short*)d_ws;       // [B][H][NQ][16]  8.4 MB
  unsigned short* Kb = Qb + 32*8*1024*16;           // [B][H][T][16]   8.4 MB
  unsigned short* Vt = Kb + 32*8*1024*16;           // [B][H][16][T]   8.4 MB
  unsigned short* hd = Vt + 32*8*1024*16;           // [B*NQ][128]     8.4 MB
  unsigned long long* mp64 = (unsigned long long*)(hd + 32768*128); // 4.2 MB

  maskpack_k<<<2048, 256, 0, stream>>>(mk, mp64);
  proj_k<<<1536, 256, 0, stream>>>(q, hh, wq, wk, wv, Qb, Kb, Vt);
  attn_k<<<4096, 64, 0, stream>>>(Qb, Kb, Vt, mp64, hd);
  outproj_k<<<512, 256, 0, stream>>>(hd, wo, out);
}

// Round 10
// 292.791 us; speedup vs baseline: 1.0144x; 1.0144x over previous
//
#include <hip/hip_runtime.h>
#include <hip/hip_bf16.h>
#include <stdint.h>

// MultiHeadAttention: B=32, NQ=T=1024, E=128, H=8, dk=dv=16
// Inputs FLOAT32, output FLOAT32. Internal bf16 MFMA.
// S^T via mfma_f32_32x32x16_bf16 (K=16 == dk); PV + denom via 16x16x32.
// Softmax exp2-domain, NO max-bias (self-normalizing: P=2^s up to ~2^23
// fits bf16; denominator division restores scale). LUT AND-masking.
// v10 = EXACT R8 revert (best measured 293.5 us):
//   - fused projmask grid (R9 split regressed +3.5: mask blocks are the
//     grid tail and overlap proj drain; split only added a launch boundary)
//   - attn v8: 64 q/wave, 1 wave/block, 4096 blocks, XCD swizzle, s_setprio,
//     single-buffered K/V/mask with placed prefetch, no cb16 bank,
//     __launch_bounds__(64,4) (valid only because live set dieted <=128).
// R2 lesson: VGPR floor below natural live set spills catastrophically.
// R4 lesson: 4-wave LDS-staged K/V regressed; 1-wave reg-resident is right.
// 3 launches: projqkv+maskpack -> flash-attn -> out-proj.

typedef __attribute__((ext_vector_type(8))) short bf16x8;    // MFMA A/B frag
typedef __attribute__((ext_vector_type(4))) float f32x4;     // 16x16 C/D frag
typedef __attribute__((ext_vector_type(16))) float f32x16;   // 32x32 C/D frag

#define QSCALE 0.36067376022224085f   // (1/sqrt(16)) * log2(e)
#define EXP2(x) __builtin_amdgcn_exp2f(x)   // raw v_exp_f32 (2^x)
#define PSTRIDE 68                     // ushorts; 34 dwords = 2 mod 32 banks

__device__ __forceinline__ unsigned short f2bf(float x) {
  union { __hip_bfloat16 h; unsigned short u; } cv;
  cv.h = __float2bfloat16(x);
  return cv.u;
}
// pack two f32 -> two bf16 (round-half-up): low=a, high=b
__device__ __forceinline__ unsigned int pk2bf(float a, float b) {
  unsigned int ua = __float_as_uint(a) + 0x8000u;
  unsigned int ub = __float_as_uint(b) + 0x8000u;
  return __builtin_amdgcn_perm(ub, ua, 0x07060302u);
}
// pack two f32 -> two bf16 (truncate; 1 instr): low=a, high=b
__device__ __forceinline__ unsigned int pk2bf_t(float a, float b) {
  return __builtin_amdgcn_perm(__float_as_uint(b), __float_as_uint(a), 0x07060302u);
}

// ---------------- fused Q/K/V projection + mask packing (one grid) ----------------
// blocks 0..1535: sel = x>>9 -> Q / K / V^T projection (64-row tile each)
// blocks 1536..3583: mask pack (64 elems/thread -> one u64 per thread)
__global__ __launch_bounds__(256) void projmask_k(const float* __restrict__ qp,
                                                  const float* __restrict__ hp,
                                                  const float* __restrict__ wqp,
                                                  const float* __restrict__ wkp,
                                                  const float* __restrict__ wvp,
                                                  const void* __restrict__ mask,
                                                  unsigned short* __restrict__ Qb,
                                                  unsigned short* __restrict__ Kb,
                                                  unsigned short* __restrict__ Vt,
                                                  unsigned long long* __restrict__ mp64) {
  __shared__ unsigned short WtLds[128 * 136];
  __shared__ __align__(16) unsigned short Cxf[9216];
  const int tid = threadIdx.x;

  if (blockIdx.x >= 1536) {   // ---------- mask-pack blocks ----------
    const int bx = blockIdx.x - 1536;   // 0..2047
    const unsigned int* mi = (const unsigned int*)mask;
    unsigned int accv = 0;
    #pragma unroll
    for (int k = 0; k < 16; ++k) accv |= mi[k * 251];
    const bool bytemode = accv > 1u;

    const long long i0 = ((long long)bx * 256 + tid) * 64;  // elem index base
    unsigned long long out = 0;
    if (bytemode) {
      const int4* mp4 = (const int4*)((const unsigned char*)mask + i0);
      #pragma unroll
      for (int j = 0; j < 4; ++j) {
        int4 w = mp4[j];
        unsigned int ws[4] = {(unsigned)w.x, (unsigned)w.y, (unsigned)w.z, (unsigned)w.w};
        unsigned long long v = 0;
        // bytes are exactly 0x00/0x01: pack 4 byte-bools -> nibble in 3 ops
        #pragma unroll
        for (int d = 0; d < 4; ++d) {
          unsigned int t = ws[d] & 0x01010101u;
          v |= (unsigned long long)((t * 0x01020408u) >> 24) << (d*4);
        }
        out |= v << (j*16);
      }
    } else {
      const int4* mp4 = (const int4*)((const int*)mask + i0);
      #pragma unroll
      for (int j = 0; j < 4; ++j) {
        unsigned long long v = 0;
        // int32 values are exactly 0/1: direct shift-or, no compares
        #pragma unroll
        for (int d = 0; d < 4; ++d) {
          int4 w = mp4[j*4 + d];
          v |= ((unsigned long long)(unsigned)w.x) << (d*4 + 0);
          v |= ((unsigned long long)(unsigned)w.y) << (d*4 + 1);
          v |= ((unsigned long long)(unsigned)w.z) << (d*4 + 2);
          v |= ((unsigned long long)(unsigned)w.w) << (d*4 + 3);
        }
        out |= v << (j*16);
      }
    }
    // thread's 64 bits are exactly u64 word (bx*256 + tid) of mp64
    mp64[(long long)bx * 256 + tid] = out;
    return;
  }

  // ---------- projection blocks ----------
  const int wave = tid >> 6, lane = tid & 63;
  const int llo4 = lane & 15, lhi4 = lane >> 4;
  const int xb = blockIdx.x & 511;
  const int sel = blockIdx.x >> 9;
  const int m0 = xb * 64;
  const int b = m0 >> 10, row0 = m0 & 1023;
  const float* A = (sel == 0) ? qp : hp;
  const float* W = (sel == 0) ? wqp : (sel == 1) ? wkp : wvp;
  const float wscale = (sel == 0) ? QSCALE : 1.0f;

  #pragma unroll
  for (int i = 0; i < 8; ++i) {
    int base = (tid + i * 256) * 8;
    float4 w0 = *(const float4*)&W[base];
    float4 w1 = *(const float4*)&W[base + 4];
    float wv8[8] = {w0.x, w0.y, w0.z, w0.w, w1.x, w1.y, w1.z, w1.w};
    // paired half-up pack: consecutive j -> consecutive kk rows, same e col
    #pragma unroll
    for (int j = 0; j < 8; j += 2) {
      unsigned int pk = pk2bf(wv8[j] * wscale, wv8[j+1] * wscale);
      int idx = base + j;
      int h = idx >> 11, e = (idx >> 4) & 127, kk = idx & 15;
      WtLds[(h*16 + kk    ) * 136 + e] = (unsigned short)pk;
      WtLds[(h*16 + kk + 1) * 136 + e] = (unsigned short)(pk >> 16);
    }
  }
  #pragma unroll
  for (int i = 0; i < 4; ++i) {
    int r = (tid >> 4) + i * 16;
    int c = (tid & 15) * 8;
    float4 a0 = *(const float4*)&A[(m0 + r) * 128 + c];
    float4 a1 = *(const float4*)&A[(m0 + r) * 128 + c + 4];
    union { unsigned int u[4]; bf16x8 v; } cvt;
    cvt.u[0] = pk2bf(a0.x, a0.y);
    cvt.u[1] = pk2bf(a0.z, a0.w);
    cvt.u[2] = pk2bf(a1.x, a1.y);
    cvt.u[3] = pk2bf(a1.z, a1.w);
    *(bf16x8*)&Cxf[r * 136 + c] = cvt.v;
  }
  __syncthreads();

  const int n0 = wave * 32;
  f32x4 acc[4][2] = {};
  #pragma unroll
  for (int kk = 0; kk < 128; kk += 32) {
    bf16x8 af[4], bfr[2];
    #pragma unroll
    for (int mi2 = 0; mi2 < 4; ++mi2)
      af[mi2] = *(const bf16x8*)&Cxf[(mi2*16 + llo4)*136 + kk + lhi4*8];
    #pragma unroll
    for (int ni = 0; ni < 2; ++ni)
      bfr[ni] = *(const bf16x8*)&WtLds[(n0 + ni*16 + llo4)*136 + kk + lhi4*8];
    #pragma unroll
    for (int mi2 = 0; mi2 < 4; ++mi2)
      #pragma unroll
      for (int ni = 0; ni < 2; ++ni)
        acc[mi2][ni] = __builtin_amdgcn_mfma_f32_16x16x32_bf16(af[mi2], bfr[ni], acc[mi2][ni], 0, 0, 0);
  }

  __syncthreads();
  if (sel < 2) {
    unsigned short* Cb = sel ? Kb : Qb;
    #pragma unroll
    for (int mi2 = 0; mi2 < 4; ++mi2)
      #pragma unroll
      for (int ni = 0; ni < 2; ++ni) {
        int n = n0 + ni*16 + llo4;
        int rb = (mi2*16 + lhi4*4);
        unsigned int p01 = pk2bf(acc[mi2][ni][0], acc[mi2][ni][1]);
        unsigned int p23 = pk2bf(acc[mi2][ni][2], acc[mi2][ni][3]);
        Cxf[(rb + 0)*136 + n] = (unsigned short)p01;
        Cxf[(rb + 1)*136 + n] = (unsigned short)(p01 >> 16);
        Cxf[(rb + 2)*136 + n] = (unsigned short)p23;
        Cxf[(rb + 3)*136 + n] = (unsigned short)(p23 >> 16);
      }
    __syncthreads();
    #pragma unroll
    for (int it = 0; it < 4; ++it) {
      int u = tid + it*256;
      int h = u >> 7, rk = u & 127, row = rk >> 1, kh = rk & 1;
      bf16x8 vv = *(const bf16x8*)&Cxf[row*136 + h*16 + kh*8];
      *(bf16x8*)&Cb[((b*8 + h)*1024 + row0 + row)*16 + kh*8] = vv;
    }
  } else {
    #pragma unroll
    for (int mi2 = 0; mi2 < 4; ++mi2)
      #pragma unroll
      for (int ni = 0; ni < 2; ++ni) {
        int n = n0 + ni*16 + llo4;
        uint2 pk;
        pk.x = pk2bf(acc[mi2][ni][0], acc[mi2][ni][1]);
        pk.y = pk2bf(acc[mi2][ni][2], acc[mi2][ni][3]);
        *(uint2*)&Cxf[n*72 + mi2*16 + lhi4*4] = pk;
      }
    __syncthreads();
    #pragma unroll
    for (int it = 0; it < 4; ++it) {
      int u = tid + it*256;
      int n = u >> 3, tc = u & 7;
      int h = n >> 4, k = n & 15;
      bf16x8 vv = *(const bf16x8*)&Cxf[n*72 + tc*8];
      *(bf16x8*)&Vt[((b*8 + h)*16 + k)*1024 + row0 + tc*8] = vv;
    }
  }
}

// ---------------- flash attention (1 wave/block, 64 q/wave, LUT mask) ----------------
// 4096 blocks (1-D). XCD-swizzled so each XCD owns whole (b,h) K/V panels.
// Single-buffered K/V/mask with placed prefetch. No softmax bias (see header).
__global__ __launch_bounds__(64, 4) void attn_k(const unsigned short* __restrict__ Qb,
                                                const unsigned short* __restrict__ Kb,
                                                const unsigned short* __restrict__ Vtb,
                                                const unsigned long long* __restrict__ mp64,
                                                unsigned short* __restrict__ heads) {
  __shared__ __align__(16) unsigned short Pw[32 * PSTRIDE]; // [q32][t64]
  __shared__ __align__(8) uint2 mlut[16];  // nibble -> 4 halfword AND-masks
  const int lane = threadIdx.x;
  const int llo4 = lane & 15, lhi4 = lane >> 4;
  const int llo5 = lane & 31, lhi5 = lane >> 5;
  // bijective XCD swizzle: 4096 blocks, 8 XCDs -> 512 contiguous per XCD
  const int bid = blockIdx.x;
  const int nid = (bid & 7) * 512 + (bid >> 3);
  const int q0 = (nid & 15) * 64;       // q-tile fastest: 16 tiles share (b,h)
  const int b  = (nid >> 4) & 31;
  const int h  = nid >> 9;
  const int bh = b * 8 + h;
  const unsigned long long* mp_base = &mp64[((b << 10) + q0 + llo5) * 16];
  const unsigned short* Kbase = &Kb[(bh * 1024 + llo5) * 16 + lhi5 * 8];
  const unsigned short* Vbase = &Vtb[(bh * 16 + llo4) * 1024 + lhi4 * 8];

  if (lane < 16) {
    unsigned int n = lane;
    unsigned int h0 = (n & 1u) ? 0u : 0xFFFFu;
    unsigned int h1 = (n & 2u) ? 0u : 0xFFFFu;
    unsigned int h2 = (n & 4u) ? 0u : 0xFFFFu;
    unsigned int h3 = (n & 8u) ? 0u : 0xFFFFu;
    mlut[lane] = make_uint2(h0 | (h1 << 16), h2 | (h3 << 16));
  }
  // single wave: LDS write->read ordering handled by in-order DS, no barrier

  // Q^T B-frags for the two q-halves (32 q wide each, k = lhi5*8+j covers dk=16)
  bf16x8 qf[2];
  #pragma unroll
  for (int qh = 0; qh < 2; ++qh)
    qf[qh] = *(const bf16x8*)&Qb[(bh * 1024 + q0 + qh*32 + llo5) * 16 + lhi5 * 8];

  bf16x8 ones;
  #pragma unroll
  for (int j = 0; j < 8; ++j) ones[j] = (short)0x3F80;  // bf16 1.0

  f32x4 ot[2][2] = {};    // O^T per [q-half][16-q frag]
  f32x4 lacc[2][2] = {};  // denominators

  // S-MFMA (zero C aliasing D; no bias) + exp2 + LUT-mask + pack to Pw
  auto spack = [&](const bf16x8& kfr, const bf16x8& q8, unsigned int mhalf, int ttp) {
    f32x16 st = {};   // C=0 aliased with D: no constant register bank
    __builtin_amdgcn_s_setprio(1);
    st = __builtin_amdgcn_mfma_f32_32x32x16_bf16(kfr, q8, st, 0, 0, 0);
    __builtin_amdgcn_s_setprio(0);
    const unsigned int m32 = mhalf >> (lhi5 * 4);
    #pragma unroll
    for (int g = 0; g < 4; ++g) {
      unsigned int nib = (m32 >> (g*8)) & 0xFu;
      uint2 am = mlut[nib];
      uint2 d;
      d.x = pk2bf_t(EXP2(st[g*4 + 0]), EXP2(st[g*4 + 1])) & am.x;
      d.y = pk2bf_t(EXP2(st[g*4 + 2]), EXP2(st[g*4 + 3])) & am.y;
      *(uint2*)&Pw[llo5 * PSTRIDE + ttp*32 + lhi5*4 + g*8] = d;
    }
  };
  // O^T += V^T * P^T ; l += ones * P^T
  auto pv = [&](f32x4 (&otq)[2], f32x4 (&laq)[2], const bf16x8& v0, const bf16x8& v1) {
    __builtin_amdgcn_s_setprio(1);
    #pragma unroll
    for (int kt = 0; kt < 2; ++kt) {
      const bf16x8& vv = kt ? v1 : v0;
      #pragma unroll
      for (int qn = 0; qn < 2; ++qn) {
        const unsigned short* pp = &Pw[(qn*16 + llo4) * PSTRIDE + kt*32 + lhi4*8];
        uint2 p0 = *(const uint2*)pp;
        uint2 p1 = *(const uint2*)(pp + 4);
        union { uint2 u[2]; bf16x8 v; } pf;
        pf.u[0] = p0; pf.u[1] = p1;
        otq[qn] = __builtin_amdgcn_mfma_f32_16x16x32_bf16(vv,   pf.v, otq[qn], 0, 0, 0);
        laq[qn] = __builtin_amdgcn_mfma_f32_16x16x32_bf16(ones, pf.v, laq[qn], 0, 0, 0);
      }
    }
    __builtin_amdgcn_s_setprio(0);
  };

  // prologue: tile-0 K/V/mask (single buffers)
  bf16x8 kf0 = *(const bf16x8*)&Kbase[0];
  bf16x8 kf1 = *(const bf16x8*)&Kbase[32 * 16];
  bf16x8 vf0 = *(const bf16x8*)&Vbase[0];
  bf16x8 vf1 = *(const bf16x8*)&Vbase[32];
  unsigned long long mw0 = mp_base[0];
  unsigned long long mw1 = mp_base[512];

  #pragma unroll 1
  for (int tw = 0; tw < 16; ++tw) {
    const int tn = (tw + 1) & 15;   // wrap keeps last prefetch in-bounds

    // qh0: S + pack + PV
    spack(kf0, qf[0], (unsigned int)mw0, 0);
    spack(kf1, qf[0], (unsigned int)(mw0 >> 32), 1);
    pv(ot[0], lacc[0], vf0, vf1);
    // qh1: S + pack
    spack(kf0, qf[1], (unsigned int)mw1, 0);
    spack(kf1, qf[1], (unsigned int)(mw1 >> 32), 1);
    // kf/mw dead here -> prefetch next tile into the SAME registers
    // (latency covered by qh1's PV below)
    kf0 = *(const bf16x8*)&Kbase[(tn * 64) * 16];
    kf1 = *(const bf16x8*)&Kbase[(tn * 64 + 32) * 16];
    mw0 = mp_base[tn];
    mw1 = mp_base[512 + tn];
    // qh1: PV
    pv(ot[1], lacc[1], vf0, vf1);
    // vf dead here -> prefetch next V (covered by next tile's qh0 S+pack)
    vf0 = *(const bf16x8*)&Vbase[tn * 64];
    vf1 = *(const bf16x8*)&Vbase[tn * 64 + 32];
  }

  #pragma unroll
  for (int qh = 0; qh < 2; ++qh)
    #pragma unroll
    for (int qn = 0; qn < 2; ++qn) {
      float l = lacc[qh][qn][0];
      float inv = l > 0.f ? 1.f / l : 0.f;
      f32x4 o = ot[qh][qn] * inv;
      uint2 d;
      d.x = pk2bf(o[0], o[1]);
      d.y = pk2bf(o[2], o[3]);
      *(uint2*)&heads[((b << 10) + q0 + qh*32 + qn*16 + llo4) * 128 + h*16 + lhi4*4] = d;
    }
}

// ---------------- output projection ----------------
__global__ __launch_bounds__(256) void outproj_k(const unsigned short* __restrict__ Av,
                                                 const float* __restrict__ W,
                                                 float* __restrict__ Co) {
  __shared__ unsigned short WtLds[128 * 136];
  __shared__ __align__(16) unsigned short Cxf[9216];
  const int tid = threadIdx.x;
  const int wave = tid >> 6, lane = tid & 63;
  const int llo4 = lane & 15, lhi4 = lane >> 4;
  const int m0 = blockIdx.x * 64;

  #pragma unroll
  for (int i = 0; i < 8; ++i) {
    int base = (tid + i * 256) * 8;
    float4 w0 = *(const float4*)&W[base];
    float4 w1 = *(const float4*)&W[base + 4];
    float wv8[8] = {w0.x, w0.y, w0.z, w0.w, w1.x, w1.y, w1.z, w1.w};
    // paired pack: consecutive idx -> consecutive rows, same col
    #pragma unroll
    for (int j = 0; j < 8; j += 2) {
      unsigned int pk = pk2bf(wv8[j], wv8[j+1]);
      int idx = base + j;
      WtLds[((idx & 127)    ) * 136 + (idx >> 7)] = (unsigned short)pk;
      WtLds[((idx & 127) + 1) * 136 + (idx >> 7)] = (unsigned short)(pk >> 16);
    }
  }
  #pragma unroll
  for (int i = 0; i < 4; ++i) {
    int r = (tid >> 4) + i * 16;
    int c = (tid & 15) * 8;
    *(bf16x8*)&Cxf[r * 136 + c] = *(const bf16x8*)&Av[(m0 + r) * 128 + c];
  }
  __syncthreads();

  const int n0 = wave * 32;
  f32x4 acc[4][2] = {};
  #pragma unroll
  for (int kk = 0; kk < 128; kk += 32) {
    bf16x8 af[4], bfr[2];
    #pragma unroll
    for (int mi2 = 0; mi2 < 4; ++mi2)
      af[mi2] = *(const bf16x8*)&Cxf[(mi2*16 + llo4)*136 + kk + lhi4*8];
    #pragma unroll
    for (int ni = 0; ni < 2; ++ni)
      bfr[ni] = *(const bf16x8*)&WtLds[(n0 + ni*16 + llo4)*136 + kk + lhi4*8];
    #pragma unroll
    for (int mi2 = 0; mi2 < 4; ++mi2)
      #pragma unroll
      for (int ni = 0; ni < 2; ++ni)
        acc[mi2][ni] = __builtin_amdgcn_mfma_f32_16x16x32_bf16(af[mi2], bfr[ni], acc[mi2][ni], 0, 0, 0);
  }
  #pragma unroll
  for (int mi2 = 0; mi2 < 4; ++mi2)
    #pragma unroll
    for (int ni = 0; ni < 2; ++ni) {
      int n = n0 + ni*16 + llo4;
      int mbase = m0 + mi2*16 + lhi4*4;
      #pragma unroll
      for (int r = 0; r < 4; ++r)
        Co[(mbase + r) * 128 + n] = acc[mi2][ni][r];
    }
}

extern "C" void kernel_launch(void* const* d_in, const int* in_sizes, int n_in,
                              void* d_out, int out_size, void* d_ws, size_t ws_size,
                              hipStream_t stream) {
  const float* q  = (const float*)d_in[0];
  const float* hh = (const float*)d_in[1];
  const void*  mk = d_in[2];
  const float* wq = (const float*)d_in[3];
  const float* wk = (const float*)d_in[4];
  const float* wv = (const float*)d_in[5];
  const float* wo = (const float*)d_in[6];
  float* out = (float*)d_out;

  unsigned short* Qb = (unsigned short*)d_ws;       // [B][H][NQ][16]  8.4 MB
  unsigned short* Kb = Qb + 32*8*1024*16;           // [B][H][T][16]   8.4 MB
  unsigned short* Vt = Kb + 32*8*1024*16;           // [B][H][16][T]   8.4 MB
  unsigned short* hd = Vt + 32*8*1024*16;           // [B*NQ][128]     8.4 MB
  unsigned long long* mp64 = (unsigned long long*)(hd + 32768*128); // 4.2 MB

  projmask_k<<<3584, 256, 0, stream>>>(q, hh, wq, wk, wv, mk, Qb, Kb, Vt, mp64);
  attn_k<<<4096, 64, 0, stream>>>(Qb, Kb, Vt, mp64, hd);
  outproj_k<<<512, 256, 0, stream>>>(hd, wo, out);
}